// Round 17
// baseline (398.028 us; speedup 1.0000x reference)
//
#include <hip/hip_runtime.h>
#include <hip/hip_bf16.h>
#include <math.h>

constexpr int N_SEQ = 8192;
constexpr int D     = 512;
constexpr int NH    = 8;
constexpr int FFDIM = 2048;
constexpr int LLMD  = 4096;
constexpr int NLAYER= 2;

typedef __bf16 bf16x8 __attribute__((ext_vector_type(8)));
typedef float  f32x4  __attribute__((ext_vector_type(4)));
typedef unsigned short u16x8 __attribute__((ext_vector_type(8)));

__device__ __forceinline__ unsigned short f2bf(float x) {
  unsigned u = __builtin_bit_cast(unsigned, x);
  unsigned r = (u + 0x7FFFu + ((u >> 16) & 1u)) >> 16;
  return (unsigned short)r;
}
__device__ __forceinline__ float bf2f(unsigned short u) {
  unsigned x = ((unsigned)u) << 16;
  return __builtin_bit_cast(float, x);
}

#define GLOAD16(g, l)                                                        \
  __builtin_amdgcn_global_load_lds(                                          \
      (const __attribute__((address_space(1))) void*)(g),                    \
      (__attribute__((address_space(3))) void*)(l), 16, 0, 0)

// ---------------------------------------------------------------------------
// Merged prep kernel: bids [0,8192) = weight transpose fp32->bf16 [N][K];
// bids [8192,10240) = x+PE -> Xr bf16 (residual), LN1 -> Hb bf16.
// ---------------------------------------------------------------------------
__global__ __launch_bounds__(256) void prep_kernel(const float* __restrict__ Wq,
                                                   const float* __restrict__ Wk,
                                                   const float* __restrict__ Wv,
                                                   const float* __restrict__ Wo,
                                                   const float* __restrict__ W1,
                                                   const float* __restrict__ W2,
                                                   const float* __restrict__ Wp,
                                                   unsigned short* __restrict__ WT,
                                                   const float* __restrict__ xin,
                                                   unsigned short* __restrict__ Xr,
                                                   unsigned short* __restrict__ Hb,
                                                   const float* __restrict__ g,
                                                   const float* __restrict__ b) {
  int bid = blockIdx.x;
  if (bid >= 8192) {
    int row  = ((bid - 8192) * 256 + (int)threadIdx.x) >> 6;
    int lane = threadIdx.x & 63;
    const float* p = xin + (size_t)row * D + lane * 8;
    float x[8];
#pragma unroll
    for (int i = 0; i < 8; ++i) {
      int d = lane * 8 + i;
      float freq = __expf((float)(d & ~1) * (-9.210340371976184f / 512.0f));
      float arg = (float)row * freq;
      float pe = (d & 1) ? cosf(arg) : sinf(arg);
      x[i] = p[i] + pe;
    }
    float s = 0.f, sq = 0.f;
#pragma unroll
    for (int i = 0; i < 8; ++i) { s += x[i]; sq += x[i] * x[i]; }
#pragma unroll
    for (int o = 32; o > 0; o >>= 1) { s += __shfl_xor(s, o); sq += __shfl_xor(sq, o); }
    float mu  = s * (1.0f / D);
    float var = sq * (1.0f / D) - mu * mu;
    float rs  = rsqrtf(var + 1e-5f);
    u16x8 xr, r;
#pragma unroll
    for (int i = 0; i < 8; ++i) {
      xr[i] = f2bf(x[i]);
      r[i]  = f2bf((x[i] - mu) * rs * g[lane * 8 + i] + b[lane * 8 + i]);
    }
    *(u16x8*)(Xr + (size_t)row * D + lane * 8) = xr;
    *(u16x8*)(Hb + (size_t)row * D + lane * 8) = r;
    return;
  }
  const float* src; unsigned short* dst; int K, N, tile;
  if (bid < 2048) {
    int mat = bid >> 8; int w = mat >> 1, l = mat & 1;
    const float* s4 = (w == 0) ? Wq : (w == 1) ? Wk : (w == 2) ? Wv : Wo;
    src = s4 + (size_t)l * 262144;
    dst = WT + ((size_t)l * 4 + w) * 262144;
    K = 512; N = 512; tile = bid & 255;
  } else if (bid < 4096) {
    int b2 = bid - 2048; int l = b2 >> 10;
    src = W1 + (size_t)l * 1048576; dst = WT + 2097152 + (size_t)l * 1048576;
    K = 512; N = 2048; tile = b2 & 1023;
  } else if (bid < 6144) {
    int b2 = bid - 4096; int l = b2 >> 10;
    src = W2 + (size_t)l * 1048576; dst = WT + 4194304 + (size_t)l * 1048576;
    K = 2048; N = 512; tile = b2 & 1023;
  } else {
    src = Wp; dst = WT + 6291456; K = 512; N = 4096; tile = bid - 6144;
  }
  int tilesN = N >> 5;
  int bk = (tile / tilesN) << 5, bn = (tile % tilesN) << 5;
  __shared__ float s[32][33];
  int r = threadIdx.x >> 5, c = threadIdx.x & 31;
#pragma unroll
  for (int i = 0; i < 4; ++i)
    s[r + 8 * i][c] = src[(size_t)(bk + r + 8 * i) * N + bn + c];
  __syncthreads();
#pragma unroll
  for (int i = 0; i < 4; ++i) {
    int rr = r + 8 * i;
    dst[(size_t)(bn + rr) * K + bk + c] = f2bf(s[c][rr]);
  }
}

// ---------------------------------------------------------------------------
// LayerNorm over bf16 input: one wave per row of 512; bf16 output
// ---------------------------------------------------------------------------
__global__ __launch_bounds__(256) void ln_bf16(const unsigned short* __restrict__ in,
                                               unsigned short* __restrict__ out,
                                               const float* __restrict__ g,
                                               const float* __restrict__ b) {
  int row  = (blockIdx.x * 256 + threadIdx.x) >> 6;
  int lane = threadIdx.x & 63;
  u16x8 v = *(const u16x8*)(in + (size_t)row * D + lane * 8);
  float x[8];
#pragma unroll
  for (int i = 0; i < 8; ++i) x[i] = bf2f(v[i]);
  float s = 0.f, sq = 0.f;
#pragma unroll
  for (int i = 0; i < 8; ++i) { s += x[i]; sq += x[i] * x[i]; }
#pragma unroll
  for (int o = 32; o > 0; o >>= 1) { s += __shfl_xor(s, o); sq += __shfl_xor(sq, o); }
  float mu  = s * (1.0f / D);
  float var = sq * (1.0f / D) - mu * mu;
  float rs  = rsqrtf(var + 1e-5f);
  f32x4 g0 = *(const f32x4*)(g + lane * 8);
  f32x4 g1 = *(const f32x4*)(g + lane * 8 + 4);
  f32x4 b0 = *(const f32x4*)(b + lane * 8);
  f32x4 b1 = *(const f32x4*)(b + lane * 8 + 4);
  u16x8 r;
#pragma unroll
  for (int i = 0; i < 4; ++i) r[i]     = f2bf((x[i] - mu) * rs * g0[i] + b0[i]);
#pragma unroll
  for (int i = 0; i < 4; ++i) r[i + 4] = f2bf((x[i + 4] - mu) * rs * g1[i] + b1[i]);
  *(u16x8*)(out + (size_t)row * D + lane * 8) = r;
}

// ---------------------------------------------------------------------------
// bf16 MFMA GEMM, 128 x BN tile, counted-vmcnt ring pipeline (T4) + T1 swizzle.
// BN=128: 3-buffer ring, vmcnt(4). BN=64: 4-buffer ring, vmcnt(6).
// Stage issued immediately after the barrier (before ds_reads): target buffer's
// last reader finished before the barrier we just crossed -> no WAR hazard,
// and the VM loads are in flight before the lgkm-bound ds_read burst.
// FLAGS: 1 bias, 2 GELU, 4 residual(bf16 resb, in-place safe), 8 bf16 out,
//        16 skip fp32 C.
// ---------------------------------------------------------------------------
template <int FLAGS, int BN>
__global__ __launch_bounds__(256) void mgemm2(const unsigned short* __restrict__ A,
                                              const unsigned short* __restrict__ Bt,
                                              const float* __restrict__ bias,
                                              const unsigned short* __restrict__ resb,
                                              float* __restrict__ C,
                                              unsigned short* __restrict__ Cb,
                                              int M, int N, int K) {
  constexpr int WNI  = BN / 32;
  constexpr int NBUF = (BN == 128) ? 3 : 4;
  __shared__ unsigned short As[NBUF][128][32];
  __shared__ unsigned short Bs[NBUF][BN][32];
  const int tid = threadIdx.x;
  const int lane = tid & 63, wv = tid >> 6;
  const int nwg = gridDim.x * gridDim.y;
  int bid = blockIdx.y * gridDim.x + blockIdx.x;
  bid = (bid & 7) * (nwg >> 3) + (bid >> 3);
  const int bm = (bid / gridDim.x) * 128, bn = (bid % gridDim.x) * BN;
  const int wr = (wv >> 1) * 64, wc = (wv & 1) * (BN / 2);
  f32x4 acc[4][WNI] = {};

  const int srA = wv * 32 + (lane >> 2);
  const int sc  = (lane & 3) * 8;
  const unsigned short* Ap0 = A + (size_t)(bm + srA) * K + sc;
  const unsigned short* Ap1 = Ap0 + (size_t)16 * K;
  const int srB = wv * (BN / 4) + (lane >> 2);
  const unsigned short* Bp0 = Bt + (size_t)(bn + srB) * K + sc;
  const unsigned short* Bp1 = Bp0 + (size_t)16 * K;
  const int kh = (lane >> 4) * 8;
  const int fr = lane & 15;

  auto stage = [&](int bb, int k0) {
    GLOAD16(Ap0 + k0, &As[bb][srA][sc]);
    GLOAD16(Ap1 + k0, &As[bb][srA + 16][sc]);
    GLOAD16(Bp0 + k0, &Bs[bb][srB][sc]);
    if constexpr (BN == 128) GLOAD16(Bp1 + k0, &Bs[bb][srB + 16][sc]);
  };

  const int nt = K >> 5;
#pragma unroll
  for (int i = 0; i < NBUF - 1; ++i) stage(i, i << 5);
  int cur = 0;
  for (int t = 0; t < nt; ++t) {
    __builtin_amdgcn_sched_barrier(0);
    if constexpr (BN == 128)
      asm volatile("s_waitcnt vmcnt(4)" ::: "memory");
    else
      asm volatile("s_waitcnt vmcnt(6)" ::: "memory");
    __builtin_amdgcn_s_barrier();
    __builtin_amdgcn_sched_barrier(0);
    if (t + NBUF - 1 < nt) {
      int tgt = cur - 1; if (tgt < 0) tgt += NBUF;   // (cur+NBUF-1)%NBUF
      stage(tgt, (t + NBUF - 1) << 5);
    }
    bf16x8 af[4], bfv[WNI];
#pragma unroll
    for (int mi = 0; mi < 4; ++mi)
      af[mi] = *(const bf16x8*)&As[cur][wr + mi * 16 + fr][kh];
#pragma unroll
    for (int ni = 0; ni < WNI; ++ni)
      bfv[ni] = *(const bf16x8*)&Bs[cur][wc + ni * 16 + fr][kh];
#pragma unroll
    for (int mi = 0; mi < 4; ++mi)
#pragma unroll
      for (int ni = 0; ni < WNI; ++ni)
        acc[mi][ni] = __builtin_amdgcn_mfma_f32_16x16x32_bf16(af[mi], bfv[ni], acc[mi][ni], 0, 0, 0);
    ++cur; if (cur == NBUF) cur = 0;
  }

  const int r4 = (lane >> 4) * 4, cc = lane & 15;
#pragma unroll
  for (int mi = 0; mi < 4; ++mi) {
#pragma unroll
    for (int ni = 0; ni < WNI; ++ni) {
      int col = bn + wc + ni * 16 + cc;
      float bsv = (FLAGS & 1) ? bias[col] : 0.0f;
      f32x4 v = acc[mi][ni];
#pragma unroll
      for (int j = 0; j < 4; ++j) {
        int row = bm + wr + mi * 16 + r4 + j;
        float x = v[j] + bsv;
        if (FLAGS & 2) x = 0.5f * x * (1.0f + erff(x * 0.7071067811865475f));
        if (FLAGS & 4) x += bf2f(resb[(size_t)row * N + col]);
        if (!(FLAGS & 16)) C[(size_t)row * N + col] = x;
        if (FLAGS & 8) Cb[(size_t)row * N + col] = f2bf(x);
      }
    }
  }
}

// ---------------------------------------------------------------------------
// Fused QKV GEMM (N=1536), 3-buffer ring + T1 XCD swizzle, stage-early.
// Q-softmax->bf16, K raw bf16 + column stats, V bf16.
// ---------------------------------------------------------------------------
__global__ __launch_bounds__(256) void qkv_gemm(const unsigned short* __restrict__ A,
                                                const unsigned short* __restrict__ Bt,
                                                unsigned short* __restrict__ Qb,
                                                unsigned short* __restrict__ Kb,
                                                unsigned short* __restrict__ Vb,
                                                float* __restrict__ pm,
                                                float* __restrict__ ps) {
  constexpr int K = 512;
  __shared__ unsigned short As[3][128][32];
  __shared__ unsigned short Bs[3][128][32];
  const int tid = threadIdx.x;
  const int lane = tid & 63, wv = tid >> 6;
  const int nwg = gridDim.x * gridDim.y;
  int bid = blockIdx.y * gridDim.x + blockIdx.x;
  bid = (bid & 7) * (nwg >> 3) + (bid >> 3);
  const int bm = (bid / gridDim.x) * 128, bn = (bid % gridDim.x) * 128;
  const int bmy = bid / gridDim.x;
  const int wr = (wv >> 1) * 64, wc = (wv & 1) * 64;
  f32x4 acc[4][4] = {};

  const int srA = wv * 32 + (lane >> 2);
  const int sc  = (lane & 3) * 8;
  const unsigned short* Ap0 = A + (size_t)(bm + srA) * K + sc;
  const unsigned short* Ap1 = Ap0 + (size_t)16 * K;
  const unsigned short* Bp0 = Bt + (size_t)(bn + srA) * K + sc;
  const unsigned short* Bp1 = Bp0 + (size_t)16 * K;
  const int kh = (lane >> 4) * 8;
  const int fr = lane & 15;

  auto stage = [&](int bb, int k0) {
    GLOAD16(Ap0 + k0, &As[bb][srA][sc]);
    GLOAD16(Ap1 + k0, &As[bb][srA + 16][sc]);
    GLOAD16(Bp0 + k0, &Bs[bb][srA][sc]);
    GLOAD16(Bp1 + k0, &Bs[bb][srA + 16][sc]);
  };

  stage(0, 0);
  stage(1, 32);
  int cur = 0;
  for (int t = 0; t < 16; ++t) {
    __builtin_amdgcn_sched_barrier(0);
    asm volatile("s_waitcnt vmcnt(4)" ::: "memory");
    __builtin_amdgcn_s_barrier();
    __builtin_amdgcn_sched_barrier(0);
    if (t + 2 < 16) {
      int tgt = cur - 1; if (tgt < 0) tgt += 3;
      stage(tgt, (t + 2) << 5);
    }
    bf16x8 af[4], bfv[4];
#pragma unroll
    for (int mi = 0; mi < 4; ++mi)
      af[mi] = *(const bf16x8*)&As[cur][wr + mi * 16 + fr][kh];
#pragma unroll
    for (int ni = 0; ni < 4; ++ni)
      bfv[ni] = *(const bf16x8*)&Bs[cur][wc + ni * 16 + fr][kh];
#pragma unroll
    for (int mi = 0; mi < 4; ++mi)
#pragma unroll
      for (int ni = 0; ni < 4; ++ni)
        acc[mi][ni] = __builtin_amdgcn_mfma_f32_16x16x32_bf16(af[mi], bfv[ni], acc[mi][ni], 0, 0, 0);
    ++cur; if (cur == 3) cur = 0;
  }

  const int r4 = (lane >> 4) * 4, cc = lane & 15;
  if (bn < 512) {
#pragma unroll
    for (int mi = 0; mi < 4; ++mi) {
#pragma unroll
      for (int j = 0; j < 4; ++j) {
        float v0 = acc[mi][0][j], v1 = acc[mi][1][j];
        float v2 = acc[mi][2][j], v3 = acc[mi][3][j];
        float m = fmaxf(fmaxf(v0, v1), fmaxf(v2, v3));
        m = fmaxf(m, __shfl_xor(m, 1)); m = fmaxf(m, __shfl_xor(m, 2));
        m = fmaxf(m, __shfl_xor(m, 4)); m = fmaxf(m, __shfl_xor(m, 8));
        float e0 = __expf(v0 - m), e1 = __expf(v1 - m);
        float e2 = __expf(v2 - m), e3 = __expf(v3 - m);
        float s = e0 + e1 + e2 + e3;
        s += __shfl_xor(s, 1); s += __shfl_xor(s, 2);
        s += __shfl_xor(s, 4); s += __shfl_xor(s, 8);
        float w = 0.125f / s;
        int row = bm + wr + mi * 16 + r4 + j;
        unsigned short* qr = Qb + (size_t)row * 512 + bn + wc + cc;
        qr[0] = f2bf(e0 * w); qr[16] = f2bf(e1 * w);
        qr[32] = f2bf(e2 * w); qr[48] = f2bf(e3 * w);
      }
    }
  } else if (bn < 1024) {
    int colb = bn - 512 + wc + cc;
    int prow = bmy * 2 + (wr ? 1 : 0);
#pragma unroll
    for (int ni = 0; ni < 4; ++ni) {
      float kf[4][4];
      float m = -1e30f;
#pragma unroll
      for (int mi = 0; mi < 4; ++mi)
#pragma unroll
        for (int j = 0; j < 4; ++j) {
          unsigned short kr = f2bf(acc[mi][ni][j]);
          Kb[(size_t)(bm + wr + mi * 16 + r4 + j) * 512 + colb + ni * 16] = kr;
          kf[mi][j] = bf2f(kr);
          m = fmaxf(m, kf[mi][j]);
        }
      m = fmaxf(m, __shfl_xor(m, 16));
      m = fmaxf(m, __shfl_xor(m, 32));
      float s = 0.f;
#pragma unroll
      for (int mi = 0; mi < 4; ++mi)
#pragma unroll
        for (int j = 0; j < 4; ++j) s += __expf(kf[mi][j] - m);
      s += __shfl_xor(s, 16);
      s += __shfl_xor(s, 32);
      if (lane < 16) {
        pm[(size_t)prow * 512 + colb + ni * 16] = m;
        ps[(size_t)prow * 512 + colb + ni * 16] = s;
      }
    }
  } else {
    int colv = bn - 1024 + wc + cc;
#pragma unroll
    for (int mi = 0; mi < 4; ++mi)
#pragma unroll
      for (int ni = 0; ni < 4; ++ni) {
        f32x4 v = acc[mi][ni];
#pragma unroll
        for (int j = 0; j < 4; ++j)
          Vb[(size_t)(bm + wr + mi * 16 + r4 + j) * 512 + colv + ni * 16] = f2bf(v[j]);
      }
  }
}

// ---------------------------------------------------------------------------
// ctx via MFMA: per (chunk,head), stats merge -> stage exp'd K^T and V^T into
// XOR-swizzled LDS -> 64x64 tile via mfma. grid (32, 8), 256 thr = 4 waves.
// ---------------------------------------------------------------------------
__global__ __launch_bounds__(256) void ctx_kernel(const unsigned short* __restrict__ kb,
                                                  const unsigned short* __restrict__ vb,
                                                  const float* __restrict__ pm,
                                                  const float* __restrict__ ps,
                                                  float* __restrict__ part) {
  int chunk = blockIdx.x, h = blockIdx.y, t = threadIdx.x;
  __shared__ unsigned short kst[64 * 256];
  __shared__ unsigned short vst[64 * 256];
  __shared__ float qm[4][64], qsum[4][64], scm[64], sci[64];
  {
    int c = t & 63, qt = t >> 6;
    float m = -1e30f, s = 0.f;
    for (int r = qt * 32; r < qt * 32 + 32; ++r) {
      float vm = pm[(size_t)r * 512 + h * 64 + c];
      float vp = ps[(size_t)r * 512 + h * 64 + c];
      float nm = fmaxf(m, vm);
      s = s * __expf(m - nm) + vp * __expf(vm - nm);
      m = nm;
    }
    qm[qt][c] = m; qsum[qt][c] = s;
  }
  __syncthreads();
  if (t < 64) {
    float M = fmaxf(fmaxf(qm[0][t], qm[1][t]), fmaxf(qm[2][t], qm[3][t]));
    float S = qsum[0][t] * __expf(qm[0][t] - M) + qsum[1][t] * __expf(qm[1][t] - M)
            + qsum[2][t] * __expf(qm[2][t] - M) + qsum[3][t] * __expf(qm[3][t] - M);
    scm[t] = M; sci[t] = 1.0f / S;
  }
  __syncthreads();
  size_t rowbase = (size_t)chunk * 256;
  for (int i = t; i < 4096; i += 256) {
    int n = i >> 4, c4 = (i & 15) * 4;
    ushort4 k4 = *(const ushort4*)&kb[(rowbase + n) * 512 + h * 64 + c4];
    ushort4 v4 = *(const ushort4*)&vb[(rowbase + n) * 512 + h * 64 + c4];
    unsigned short kr[4] = {
      f2bf(__expf(bf2f(k4.x) - scm[c4 + 0]) * sci[c4 + 0]),
      f2bf(__expf(bf2f(k4.y) - scm[c4 + 1]) * sci[c4 + 1]),
      f2bf(__expf(bf2f(k4.z) - scm[c4 + 2]) * sci[c4 + 2]),
      f2bf(__expf(bf2f(k4.w) - scm[c4 + 3]) * sci[c4 + 3])};
    unsigned short vr[4] = {v4.x, v4.y, v4.z, v4.w};
#pragma unroll
    for (int j = 0; j < 4; ++j) {
      int d = c4 + j;
      int byt = (d * 512 + n * 2) ^ ((d & 7) << 4);
      *(unsigned short*)((char*)kst + byt) = kr[j];
      *(unsigned short*)((char*)vst + byt) = vr[j];
    }
  }
  __syncthreads();
  int lane = t & 63, wv = t >> 6;
  int fr = lane & 15, kh = (lane >> 4) * 8;
  f32x4 acc[4] = {};
  int d = wv * 16 + fr;
#pragma unroll
  for (int kk = 0; kk < 8; ++kk) {
    int abyt = (d * 512 + (kk * 32 + kh) * 2) ^ ((d & 7) << 4);
    bf16x8 af = *(const bf16x8*)((const char*)kst + abyt);
#pragma unroll
    for (int ni = 0; ni < 4; ++ni) {
      int e = ni * 16 + fr;
      int bbyt = (e * 512 + (kk * 32 + kh) * 2) ^ ((e & 7) << 4);
      bf16x8 bv = *(const bf16x8*)((const char*)vst + bbyt);
      acc[ni] = __builtin_amdgcn_mfma_f32_16x16x32_bf16(af, bv, acc[ni], 0, 0, 0);
    }
  }
  int r4 = (lane >> 4) * 4, cc = lane & 15;
  float* pb = &part[((size_t)h * 32 + chunk) * 4096];
#pragma unroll
  for (int ni = 0; ni < 4; ++ni)
#pragma unroll
    for (int j = 0; j < 4; ++j)
      pb[(wv * 16 + r4 + j) * 64 + ni * 16 + cc] = acc[ni][j];
}

// ---------------------------------------------------------------------------
// ctx partial reduce: 32 chunks -> CTX[h][4096]. 128 blocks x 256 thr.
// ---------------------------------------------------------------------------
__global__ __launch_bounds__(256) void ctx_reduce_kernel(const float* __restrict__ part,
                                                         float* __restrict__ ctx) {
  int idx = blockIdx.x * 256 + threadIdx.x;   // < 8*4096
  int h = idx >> 12, de = idx & 4095;
  float s = 0.f;
#pragma unroll 8
  for (int c = 0; c < 32; ++c) s += part[((size_t)h * 32 + c) * 4096 + de];
  ctx[(size_t)h * 4096 + de] = s;
}

// ---------------------------------------------------------------------------
// ctxw2: W'_h = ctx_h @ Wo_h -> bf16 [N][K] B-operand layout.
// grid (8 coltiles, 8 heads), 256 thr. LDS-staged, conflict-free.
// ---------------------------------------------------------------------------
__global__ __launch_bounds__(256) void ctxw2_kernel(const float* __restrict__ ctx,
                                                    const float* __restrict__ Wo,
                                                    unsigned short* __restrict__ WPT) {
  int ct = blockIdx.x, h = blockIdx.y, t = threadIdx.x;
  __shared__ float cs[64][64];
  __shared__ float wo[64][64];
  for (int i = t; i < 4096; i += 256) {
    cs[i >> 6][i & 63] = ctx[(size_t)h * 4096 + i];
    wo[i >> 6][i & 63] = Wo[(size_t)(h * 64 + (i >> 6)) * 512 + ct * 64 + (i & 63)];
  }
  __syncthreads();
  int cl = t & 63, dg = (t >> 6) * 16;
  float accv[16];
#pragma unroll
  for (int j = 0; j < 16; ++j) accv[j] = 0.f;
  for (int e = 0; e < 64; ++e) {
    float w = wo[e][cl];
#pragma unroll
    for (int j = 0; j < 16; ++j) accv[j] = fmaf(cs[dg + j][e], w, accv[j]);
  }
  u16x8 o0, o1;
#pragma unroll
  for (int j = 0; j < 8; ++j) { o0[j] = f2bf(accv[j]); o1[j] = f2bf(accv[j + 8]); }
  unsigned short* dst = WPT + (size_t)(ct * 64 + cl) * 512 + h * 64 + dg;
  *(u16x8*)dst = o0;
  *(u16x8*)(dst + 8) = o1;
}

// ---------------------------------------------------------------------------
extern "C" void kernel_launch(void* const* d_in, const int* in_sizes, int n_in,
                              void* d_out, int out_size, void* d_ws, size_t ws_size,
                              hipStream_t stream) {
  const float* x_in  = (const float*)d_in[0];
  const float* ln1_g = (const float*)d_in[1];
  const float* ln1_b = (const float*)d_in[2];
  const float* Wq    = (const float*)d_in[3];
  const float* Wk    = (const float*)d_in[4];
  const float* Wv    = (const float*)d_in[5];
  const float* Wo    = (const float*)d_in[6];
  const float* bo    = (const float*)d_in[7];
  const float* ln2_g = (const float*)d_in[8];
  const float* ln2_b = (const float*)d_in[9];
  const float* W1    = (const float*)d_in[10];
  const float* b1    = (const float*)d_in[11];
  const float* W2    = (const float*)d_in[12];
  const float* b2    = (const float*)d_in[13];
  const float* projW = (const float*)d_in[14];
  const float* projb = (const float*)d_in[15];
  float* out = (float*)d_out;
  float* ws  = (float*)d_ws;
  constexpr size_t M1 = 1u << 20;

  float* CTXP = ws;                       // 1M f
  float* PM   = ws + 1 * M1;              // 64K f
  float* PS   = PM + 65536;               // 64K f
  float* CTX  = PS + 65536;               // 32K f
  unsigned short* Xr  = (unsigned short*)(ws + 2 * M1);   // 4M u16 (bf16 residual)
  unsigned short* Qb  = (unsigned short*)(ws + 4 * M1);   // 4M u16
  unsigned short* Kb  = (unsigned short*)(ws + 6 * M1);   // 4M u16
  unsigned short* Vb  = (unsigned short*)(ws + 8 * M1);   // 4M u16
  unsigned short* Hb  = (unsigned short*)(ws + 10 * M1);  // 4M u16
  unsigned short* FFH = (unsigned short*)(ws + 12 * M1);  // 16M u16
  unsigned short* WT  = (unsigned short*)(ws + 20 * M1);  // 8M u16
  unsigned short* WPT = (unsigned short*)(ws + 24 * M1);  // 256K u16 (W' 512x512)

  prep_kernel<<<10240, 256, 0, stream>>>(Wq, Wk, Wv, Wo, W1, W2, projW, WT,
                                         x_in, Xr, Hb, ln1_g, ln1_b);

  dim3 gqkv(1536 / 128, N_SEQ / 128);
  dim3 g512n(512 / 64, N_SEQ / 128);
  dim3 gff1(FFDIM / 128, N_SEQ / 128);
  dim3 gproj(LLMD / 128, N_SEQ / 128);

  for (int l = 0; l < NLAYER; ++l) {
    const unsigned short* WQKV = WT + (size_t)l * 1048576;
    const unsigned short* W1T  = WT + 2097152 + (size_t)l * 1048576;
    const unsigned short* W2T  = WT + 4194304 + (size_t)l * 1048576;

    qkv_gemm<<<gqkv, 256, 0, stream>>>(Hb, WQKV, Qb, Kb, Vb, PM, PS);
    ctx_kernel<<<dim3(32, NH), 256, 0, stream>>>(Kb, Vb, PM, PS, CTXP);
    ctx_reduce_kernel<<<128, 256, 0, stream>>>(CTXP, CTX);
    ctxw2_kernel<<<dim3(8, NH), 256, 0, stream>>>(CTX, Wo + (size_t)l * D * D, WPT);
    // x += q @ W' + bo  (bf16 residual, in-place)
    mgemm2<29, 64><<<g512n, 256, 0, stream>>>(Qb, WPT, bo + l * D, Xr, nullptr,
                                              Xr, N_SEQ, 512, 512);
    ln_bf16<<<N_SEQ / 4, 256, 0, stream>>>(Xr, Hb, ln2_g + l * D, ln2_b + l * D);
    // FF1 + bias + GELU -> FFH (bf16)
    mgemm2<27, 128><<<gff1, 256, 0, stream>>>(Hb, W1T, b1 + l * FFDIM, nullptr,
                                              nullptr, FFH, N_SEQ, FFDIM, 512);
    // FF2 + bias + residual -> Xr (bf16, in-place)
    mgemm2<29, 64><<<g512n, 256, 0, stream>>>(FFH, W2T, b2 + l * D, Xr, nullptr,
                                              Xr, N_SEQ, 512, 2048);
    if (l != NLAYER - 1)
      ln_bf16<<<N_SEQ / 4, 256, 0, stream>>>(Xr, Hb, ln1_g + (l + 1) * D,
                                             ln1_b + (l + 1) * D);
  }
  mgemm2<1, 128><<<gproj, 256, 0, stream>>>(Xr, WT + 6291456, projb, nullptr,
                                            out, nullptr, N_SEQ, LLMD, 512);
}

// Round 18
// 364.032 us; speedup vs baseline: 1.0934x; 1.0934x over previous
//
#include <hip/hip_runtime.h>
#include <hip/hip_bf16.h>
#include <math.h>

constexpr int N_SEQ = 8192;
constexpr int D     = 512;
constexpr int NH    = 8;
constexpr int FFDIM = 2048;
constexpr int LLMD  = 4096;
constexpr int NLAYER= 2;

typedef __bf16 bf16x8 __attribute__((ext_vector_type(8)));
typedef float  f32x4  __attribute__((ext_vector_type(4)));
typedef unsigned short u16x8 __attribute__((ext_vector_type(8)));

__device__ __forceinline__ unsigned short f2bf(float x) {
  unsigned u = __builtin_bit_cast(unsigned, x);
  unsigned r = (u + 0x7FFFu + ((u >> 16) & 1u)) >> 16;
  return (unsigned short)r;
}
__device__ __forceinline__ float bf2f(unsigned short u) {
  unsigned x = ((unsigned)u) << 16;
  return __builtin_bit_cast(float, x);
}

#define GLOAD16(g, l)                                                        \
  __builtin_amdgcn_global_load_lds(                                          \
      (const __attribute__((address_space(1))) void*)(g),                    \
      (__attribute__((address_space(3))) void*)(l), 16, 0, 0)

// ---------------------------------------------------------------------------
// Merged prep kernel: bids [0,8192) = weight transpose fp32->bf16 [N][K];
// bids [8192,10240) = x+PE -> Xr bf16 (residual), LN1 -> Hb bf16.
// ---------------------------------------------------------------------------
__global__ __launch_bounds__(256) void prep_kernel(const float* __restrict__ Wq,
                                                   const float* __restrict__ Wk,
                                                   const float* __restrict__ Wv,
                                                   const float* __restrict__ Wo,
                                                   const float* __restrict__ W1,
                                                   const float* __restrict__ W2,
                                                   const float* __restrict__ Wp,
                                                   unsigned short* __restrict__ WT,
                                                   const float* __restrict__ xin,
                                                   unsigned short* __restrict__ Xr,
                                                   unsigned short* __restrict__ Hb,
                                                   const float* __restrict__ g,
                                                   const float* __restrict__ b) {
  int bid = blockIdx.x;
  if (bid >= 8192) {
    int row  = ((bid - 8192) * 256 + (int)threadIdx.x) >> 6;
    int lane = threadIdx.x & 63;
    const float* p = xin + (size_t)row * D + lane * 8;
    float x[8];
#pragma unroll
    for (int i = 0; i < 8; ++i) {
      int d = lane * 8 + i;
      float freq = __expf((float)(d & ~1) * (-9.210340371976184f / 512.0f));
      float arg = (float)row * freq;
      float pe = (d & 1) ? cosf(arg) : sinf(arg);
      x[i] = p[i] + pe;
    }
    float s = 0.f, sq = 0.f;
#pragma unroll
    for (int i = 0; i < 8; ++i) { s += x[i]; sq += x[i] * x[i]; }
#pragma unroll
    for (int o = 32; o > 0; o >>= 1) { s += __shfl_xor(s, o); sq += __shfl_xor(sq, o); }
    float mu  = s * (1.0f / D);
    float var = sq * (1.0f / D) - mu * mu;
    float rs  = rsqrtf(var + 1e-5f);
    u16x8 xr, r;
#pragma unroll
    for (int i = 0; i < 8; ++i) {
      xr[i] = f2bf(x[i]);
      r[i]  = f2bf((x[i] - mu) * rs * g[lane * 8 + i] + b[lane * 8 + i]);
    }
    *(u16x8*)(Xr + (size_t)row * D + lane * 8) = xr;
    *(u16x8*)(Hb + (size_t)row * D + lane * 8) = r;
    return;
  }
  const float* src; unsigned short* dst; int K, N, tile;
  if (bid < 2048) {
    int mat = bid >> 8; int w = mat >> 1, l = mat & 1;
    const float* s4 = (w == 0) ? Wq : (w == 1) ? Wk : (w == 2) ? Wv : Wo;
    src = s4 + (size_t)l * 262144;
    dst = WT + ((size_t)l * 4 + w) * 262144;
    K = 512; N = 512; tile = bid & 255;
  } else if (bid < 4096) {
    int b2 = bid - 2048; int l = b2 >> 10;
    src = W1 + (size_t)l * 1048576; dst = WT + 2097152 + (size_t)l * 1048576;
    K = 512; N = 2048; tile = b2 & 1023;
  } else if (bid < 6144) {
    int b2 = bid - 4096; int l = b2 >> 10;
    src = W2 + (size_t)l * 1048576; dst = WT + 4194304 + (size_t)l * 1048576;
    K = 2048; N = 512; tile = b2 & 1023;
  } else {
    src = Wp; dst = WT + 6291456; K = 512; N = 4096; tile = bid - 6144;
  }
  int tilesN = N >> 5;
  int bk = (tile / tilesN) << 5, bn = (tile % tilesN) << 5;
  __shared__ float s[32][33];
  int r = threadIdx.x >> 5, c = threadIdx.x & 31;
#pragma unroll
  for (int i = 0; i < 4; ++i)
    s[r + 8 * i][c] = src[(size_t)(bk + r + 8 * i) * N + bn + c];
  __syncthreads();
#pragma unroll
  for (int i = 0; i < 4; ++i) {
    int rr = r + 8 * i;
    dst[(size_t)(bn + rr) * K + bk + c] = f2bf(s[c][rr]);
  }
}

// ---------------------------------------------------------------------------
// LayerNorm over bf16 input: one wave per row of 512; bf16 output
// ---------------------------------------------------------------------------
__global__ __launch_bounds__(256) void ln_bf16(const unsigned short* __restrict__ in,
                                               unsigned short* __restrict__ out,
                                               const float* __restrict__ g,
                                               const float* __restrict__ b) {
  int row  = (blockIdx.x * 256 + threadIdx.x) >> 6;
  int lane = threadIdx.x & 63;
  u16x8 v = *(const u16x8*)(in + (size_t)row * D + lane * 8);
  float x[8];
#pragma unroll
  for (int i = 0; i < 8; ++i) x[i] = bf2f(v[i]);
  float s = 0.f, sq = 0.f;
#pragma unroll
  for (int i = 0; i < 8; ++i) { s += x[i]; sq += x[i] * x[i]; }
#pragma unroll
  for (int o = 32; o > 0; o >>= 1) { s += __shfl_xor(s, o); sq += __shfl_xor(sq, o); }
  float mu  = s * (1.0f / D);
  float var = sq * (1.0f / D) - mu * mu;
  float rs  = rsqrtf(var + 1e-5f);
  f32x4 g0 = *(const f32x4*)(g + lane * 8);
  f32x4 g1 = *(const f32x4*)(g + lane * 8 + 4);
  f32x4 b0 = *(const f32x4*)(b + lane * 8);
  f32x4 b1 = *(const f32x4*)(b + lane * 8 + 4);
  u16x8 r;
#pragma unroll
  for (int i = 0; i < 4; ++i) r[i]     = f2bf((x[i] - mu) * rs * g0[i] + b0[i]);
#pragma unroll
  for (int i = 0; i < 4; ++i) r[i + 4] = f2bf((x[i + 4] - mu) * rs * g1[i] + b1[i]);
  *(u16x8*)(out + (size_t)row * D + lane * 8) = r;
}

// ---------------------------------------------------------------------------
// bf16 MFMA GEMM, 128 x BN tile, counted-vmcnt ring pipeline (T4) + T1 swizzle.
// BN=128: 3-buffer ring, vmcnt(4). BN=64: 4-buffer ring, vmcnt(6).
// FLAGS: 1 bias, 2 GELU, 4 residual(bf16 resb, in-place safe), 8 bf16 out,
//        16 skip fp32 C.
// ---------------------------------------------------------------------------
template <int FLAGS, int BN>
__global__ __launch_bounds__(256) void mgemm2(const unsigned short* __restrict__ A,
                                              const unsigned short* __restrict__ Bt,
                                              const float* __restrict__ bias,
                                              const unsigned short* __restrict__ resb,
                                              float* __restrict__ C,
                                              unsigned short* __restrict__ Cb,
                                              int M, int N, int K) {
  constexpr int WNI  = BN / 32;
  constexpr int NBUF = (BN == 128) ? 3 : 4;
  __shared__ unsigned short As[NBUF][128][32];
  __shared__ unsigned short Bs[NBUF][BN][32];
  const int tid = threadIdx.x;
  const int lane = tid & 63, wv = tid >> 6;
  const int nwg = gridDim.x * gridDim.y;
  int bid = blockIdx.y * gridDim.x + blockIdx.x;
  bid = (bid & 7) * (nwg >> 3) + (bid >> 3);
  const int bm = (bid / gridDim.x) * 128, bn = (bid % gridDim.x) * BN;
  const int wr = (wv >> 1) * 64, wc = (wv & 1) * (BN / 2);
  f32x4 acc[4][WNI] = {};

  const int srA = wv * 32 + (lane >> 2);
  const int sc  = (lane & 3) * 8;
  const unsigned short* Ap0 = A + (size_t)(bm + srA) * K + sc;
  const unsigned short* Ap1 = Ap0 + (size_t)16 * K;
  const int srB = wv * (BN / 4) + (lane >> 2);
  const unsigned short* Bp0 = Bt + (size_t)(bn + srB) * K + sc;
  const unsigned short* Bp1 = Bp0 + (size_t)16 * K;
  const int kh = (lane >> 4) * 8;
  const int fr = lane & 15;

  auto stage = [&](int bb, int k0) {
    GLOAD16(Ap0 + k0, &As[bb][srA][sc]);
    GLOAD16(Ap1 + k0, &As[bb][srA + 16][sc]);
    GLOAD16(Bp0 + k0, &Bs[bb][srB][sc]);
    if constexpr (BN == 128) GLOAD16(Bp1 + k0, &Bs[bb][srB + 16][sc]);
  };

  const int nt = K >> 5;
#pragma unroll
  for (int i = 0; i < NBUF - 1; ++i) stage(i, i << 5);
  int cur = 0;
  for (int t = 0; t < nt; ++t) {
    __builtin_amdgcn_sched_barrier(0);
    if constexpr (BN == 128)
      asm volatile("s_waitcnt vmcnt(4)" ::: "memory");
    else
      asm volatile("s_waitcnt vmcnt(6)" ::: "memory");
    __builtin_amdgcn_s_barrier();
    __builtin_amdgcn_sched_barrier(0);
    bf16x8 af[4], bfv[WNI];
#pragma unroll
    for (int mi = 0; mi < 4; ++mi)
      af[mi] = *(const bf16x8*)&As[cur][wr + mi * 16 + fr][kh];
#pragma unroll
    for (int ni = 0; ni < WNI; ++ni)
      bfv[ni] = *(const bf16x8*)&Bs[cur][wc + ni * 16 + fr][kh];
    if (t + NBUF - 1 < nt) {
      int tgt = cur - 1; if (tgt < 0) tgt += NBUF;
      stage(tgt, (t + NBUF - 1) << 5);
    }
#pragma unroll
    for (int mi = 0; mi < 4; ++mi)
#pragma unroll
      for (int ni = 0; ni < WNI; ++ni)
        acc[mi][ni] = __builtin_amdgcn_mfma_f32_16x16x32_bf16(af[mi], bfv[ni], acc[mi][ni], 0, 0, 0);
    ++cur; if (cur == NBUF) cur = 0;
  }

  const int r4 = (lane >> 4) * 4, cc = lane & 15;
#pragma unroll
  for (int mi = 0; mi < 4; ++mi) {
#pragma unroll
    for (int ni = 0; ni < WNI; ++ni) {
      int col = bn + wc + ni * 16 + cc;
      float bsv = (FLAGS & 1) ? bias[col] : 0.0f;
      f32x4 v = acc[mi][ni];
#pragma unroll
      for (int j = 0; j < 4; ++j) {
        int row = bm + wr + mi * 16 + r4 + j;
        float x = v[j] + bsv;
        if (FLAGS & 2) x = 0.5f * x * (1.0f + erff(x * 0.7071067811865475f));
        if (FLAGS & 4) x += bf2f(resb[(size_t)row * N + col]);
        if (!(FLAGS & 16)) C[(size_t)row * N + col] = x;
        if (FLAGS & 8) Cb[(size_t)row * N + col] = f2bf(x);
      }
    }
  }
}

// ---------------------------------------------------------------------------
// Fused QKV GEMM (N=1536), 3-buffer ring + T1 XCD swizzle.
// Q-softmax->bf16, K raw bf16 + column stats, V bf16.
// ---------------------------------------------------------------------------
__global__ __launch_bounds__(256) void qkv_gemm(const unsigned short* __restrict__ A,
                                                const unsigned short* __restrict__ Bt,
                                                unsigned short* __restrict__ Qb,
                                                unsigned short* __restrict__ Kb,
                                                unsigned short* __restrict__ Vb,
                                                float* __restrict__ pm,
                                                float* __restrict__ ps) {
  constexpr int K = 512;
  __shared__ unsigned short As[3][128][32];
  __shared__ unsigned short Bs[3][128][32];
  const int tid = threadIdx.x;
  const int lane = tid & 63, wv = tid >> 6;
  const int nwg = gridDim.x * gridDim.y;
  int bid = blockIdx.y * gridDim.x + blockIdx.x;
  bid = (bid & 7) * (nwg >> 3) + (bid >> 3);
  const int bm = (bid / gridDim.x) * 128, bn = (bid % gridDim.x) * 128;
  const int bmy = bid / gridDim.x;
  const int wr = (wv >> 1) * 64, wc = (wv & 1) * 64;
  f32x4 acc[4][4] = {};

  const int srA = wv * 32 + (lane >> 2);
  const int sc  = (lane & 3) * 8;
  const unsigned short* Ap0 = A + (size_t)(bm + srA) * K + sc;
  const unsigned short* Ap1 = Ap0 + (size_t)16 * K;
  const unsigned short* Bp0 = Bt + (size_t)(bn + srA) * K + sc;
  const unsigned short* Bp1 = Bp0 + (size_t)16 * K;
  const int kh = (lane >> 4) * 8;
  const int fr = lane & 15;

  auto stage = [&](int bb, int k0) {
    GLOAD16(Ap0 + k0, &As[bb][srA][sc]);
    GLOAD16(Ap1 + k0, &As[bb][srA + 16][sc]);
    GLOAD16(Bp0 + k0, &Bs[bb][srA][sc]);
    GLOAD16(Bp1 + k0, &Bs[bb][srA + 16][sc]);
  };

  stage(0, 0);
  stage(1, 32);
  int cur = 0;
  for (int t = 0; t < 16; ++t) {
    __builtin_amdgcn_sched_barrier(0);
    asm volatile("s_waitcnt vmcnt(4)" ::: "memory");
    __builtin_amdgcn_s_barrier();
    __builtin_amdgcn_sched_barrier(0);
    bf16x8 af[4], bfv[4];
#pragma unroll
    for (int mi = 0; mi < 4; ++mi)
      af[mi] = *(const bf16x8*)&As[cur][wr + mi * 16 + fr][kh];
#pragma unroll
    for (int ni = 0; ni < 4; ++ni)
      bfv[ni] = *(const bf16x8*)&Bs[cur][wc + ni * 16 + fr][kh];
    if (t + 2 < 16) {
      int tgt = cur - 1; if (tgt < 0) tgt += 3;
      stage(tgt, (t + 2) << 5);
    }
#pragma unroll
    for (int mi = 0; mi < 4; ++mi)
#pragma unroll
      for (int ni = 0; ni < 4; ++ni)
        acc[mi][ni] = __builtin_amdgcn_mfma_f32_16x16x32_bf16(af[mi], bfv[ni], acc[mi][ni], 0, 0, 0);
    ++cur; if (cur == 3) cur = 0;
  }

  const int r4 = (lane >> 4) * 4, cc = lane & 15;
  if (bn < 512) {
#pragma unroll
    for (int mi = 0; mi < 4; ++mi) {
#pragma unroll
      for (int j = 0; j < 4; ++j) {
        float v0 = acc[mi][0][j], v1 = acc[mi][1][j];
        float v2 = acc[mi][2][j], v3 = acc[mi][3][j];
        float m = fmaxf(fmaxf(v0, v1), fmaxf(v2, v3));
        m = fmaxf(m, __shfl_xor(m, 1)); m = fmaxf(m, __shfl_xor(m, 2));
        m = fmaxf(m, __shfl_xor(m, 4)); m = fmaxf(m, __shfl_xor(m, 8));
        float e0 = __expf(v0 - m), e1 = __expf(v1 - m);
        float e2 = __expf(v2 - m), e3 = __expf(v3 - m);
        float s = e0 + e1 + e2 + e3;
        s += __shfl_xor(s, 1); s += __shfl_xor(s, 2);
        s += __shfl_xor(s, 4); s += __shfl_xor(s, 8);
        float w = 0.125f / s;
        int row = bm + wr + mi * 16 + r4 + j;
        unsigned short* qr = Qb + (size_t)row * 512 + bn + wc + cc;
        qr[0] = f2bf(e0 * w); qr[16] = f2bf(e1 * w);
        qr[32] = f2bf(e2 * w); qr[48] = f2bf(e3 * w);
      }
    }
  } else if (bn < 1024) {
    int colb = bn - 512 + wc + cc;
    int prow = bmy * 2 + (wr ? 1 : 0);
#pragma unroll
    for (int ni = 0; ni < 4; ++ni) {
      float kf[4][4];
      float m = -1e30f;
#pragma unroll
      for (int mi = 0; mi < 4; ++mi)
#pragma unroll
        for (int j = 0; j < 4; ++j) {
          unsigned short kr = f2bf(acc[mi][ni][j]);
          Kb[(size_t)(bm + wr + mi * 16 + r4 + j) * 512 + colb + ni * 16] = kr;
          kf[mi][j] = bf2f(kr);
          m = fmaxf(m, kf[mi][j]);
        }
      m = fmaxf(m, __shfl_xor(m, 16));
      m = fmaxf(m, __shfl_xor(m, 32));
      float s = 0.f;
#pragma unroll
      for (int mi = 0; mi < 4; ++mi)
#pragma unroll
        for (int j = 0; j < 4; ++j) s += __expf(kf[mi][j] - m);
      s += __shfl_xor(s, 16);
      s += __shfl_xor(s, 32);
      if (lane < 16) {
        pm[(size_t)prow * 512 + colb + ni * 16] = m;
        ps[(size_t)prow * 512 + colb + ni * 16] = s;
      }
    }
  } else {
    int colv = bn - 1024 + wc + cc;
#pragma unroll
    for (int mi = 0; mi < 4; ++mi)
#pragma unroll
      for (int ni = 0; ni < 4; ++ni) {
        f32x4 v = acc[mi][ni];
#pragma unroll
        for (int j = 0; j < 4; ++j)
          Vb[(size_t)(bm + wr + mi * 16 + r4 + j) * 512 + colv + ni * 16] = f2bf(v[j]);
      }
  }
}

// ---------------------------------------------------------------------------
// ctx via MFMA: per (chunk,head), stats merge -> stage exp'd K^T and V^T into
// XOR-swizzled LDS -> 64x64 tile via mfma. grid (32, 8), 256 thr = 4 waves.
// ---------------------------------------------------------------------------
__global__ __launch_bounds__(256) void ctx_kernel(const unsigned short* __restrict__ kb,
                                                  const unsigned short* __restrict__ vb,
                                                  const float* __restrict__ pm,
                                                  const float* __restrict__ ps,
                                                  float* __restrict__ part) {
  int chunk = blockIdx.x, h = blockIdx.y, t = threadIdx.x;
  __shared__ unsigned short kst[64 * 256];
  __shared__ unsigned short vst[64 * 256];
  __shared__ float qm[4][64], qsum[4][64], scm[64], sci[64];
  {
    int c = t & 63, qt = t >> 6;
    float m = -1e30f, s = 0.f;
    for (int r = qt * 32; r < qt * 32 + 32; ++r) {
      float vm = pm[(size_t)r * 512 + h * 64 + c];
      float vp = ps[(size_t)r * 512 + h * 64 + c];
      float nm = fmaxf(m, vm);
      s = s * __expf(m - nm) + vp * __expf(vm - nm);
      m = nm;
    }
    qm[qt][c] = m; qsum[qt][c] = s;
  }
  __syncthreads();
  if (t < 64) {
    float M = fmaxf(fmaxf(qm[0][t], qm[1][t]), fmaxf(qm[2][t], qm[3][t]));
    float S = qsum[0][t] * __expf(qm[0][t] - M) + qsum[1][t] * __expf(qm[1][t] - M)
            + qsum[2][t] * __expf(qm[2][t] - M) + qsum[3][t] * __expf(qm[3][t] - M);
    scm[t] = M; sci[t] = 1.0f / S;
  }
  __syncthreads();
  size_t rowbase = (size_t)chunk * 256;
  for (int i = t; i < 4096; i += 256) {
    int n = i >> 4, c4 = (i & 15) * 4;
    ushort4 k4 = *(const ushort4*)&kb[(rowbase + n) * 512 + h * 64 + c4];
    ushort4 v4 = *(const ushort4*)&vb[(rowbase + n) * 512 + h * 64 + c4];
    unsigned short kr[4] = {
      f2bf(__expf(bf2f(k4.x) - scm[c4 + 0]) * sci[c4 + 0]),
      f2bf(__expf(bf2f(k4.y) - scm[c4 + 1]) * sci[c4 + 1]),
      f2bf(__expf(bf2f(k4.z) - scm[c4 + 2]) * sci[c4 + 2]),
      f2bf(__expf(bf2f(k4.w) - scm[c4 + 3]) * sci[c4 + 3])};
    unsigned short vr[4] = {v4.x, v4.y, v4.z, v4.w};
#pragma unroll
    for (int j = 0; j < 4; ++j) {
      int d = c4 + j;
      int byt = (d * 512 + n * 2) ^ ((d & 7) << 4);
      *(unsigned short*)((char*)kst + byt) = kr[j];
      *(unsigned short*)((char*)vst + byt) = vr[j];
    }
  }
  __syncthreads();
  int lane = t & 63, wv = t >> 6;
  int fr = lane & 15, kh = (lane >> 4) * 8;
  f32x4 acc[4] = {};
  int d = wv * 16 + fr;
#pragma unroll
  for (int kk = 0; kk < 8; ++kk) {
    int abyt = (d * 512 + (kk * 32 + kh) * 2) ^ ((d & 7) << 4);
    bf16x8 af = *(const bf16x8*)((const char*)kst + abyt);
#pragma unroll
    for (int ni = 0; ni < 4; ++ni) {
      int e = ni * 16 + fr;
      int bbyt = (e * 512 + (kk * 32 + kh) * 2) ^ ((e & 7) << 4);
      bf16x8 bv = *(const bf16x8*)((const char*)vst + bbyt);
      acc[ni] = __builtin_amdgcn_mfma_f32_16x16x32_bf16(af, bv, acc[ni], 0, 0, 0);
    }
  }
  int r4 = (lane >> 4) * 4, cc = lane & 15;
  float* pb = &part[((size_t)h * 32 + chunk) * 4096];
#pragma unroll
  for (int ni = 0; ni < 4; ++ni)
#pragma unroll
    for (int j = 0; j < 4; ++j)
      pb[(wv * 16 + r4 + j) * 64 + ni * 16 + cc] = acc[ni][j];
}

// ---------------------------------------------------------------------------
// ctx partial reduce: 32 chunks -> CTX[h][4096]. 128 blocks x 256 thr.
// ---------------------------------------------------------------------------
__global__ __launch_bounds__(256) void ctx_reduce_kernel(const float* __restrict__ part,
                                                         float* __restrict__ ctx) {
  int idx = blockIdx.x * 256 + threadIdx.x;   // < 8*4096
  int h = idx >> 12, de = idx & 4095;
  float s = 0.f;
#pragma unroll 8
  for (int c = 0; c < 32; ++c) s += part[((size_t)h * 32 + c) * 4096 + de];
  ctx[(size_t)h * 4096 + de] = s;
}

// ---------------------------------------------------------------------------
// ctxw2: W'_h = ctx_h @ Wo_h -> bf16 [N][K] B-operand layout.
// grid (8 coltiles, 8 heads), 256 thr. LDS-staged, conflict-free.
// ---------------------------------------------------------------------------
__global__ __launch_bounds__(256) void ctxw2_kernel(const float* __restrict__ ctx,
                                                    const float* __restrict__ Wo,
                                                    unsigned short* __restrict__ WPT) {
  int ct = blockIdx.x, h = blockIdx.y, t = threadIdx.x;
  __shared__ float cs[64][64];
  __shared__ float wo[64][64];
  for (int i = t; i < 4096; i += 256) {
    cs[i >> 6][i & 63] = ctx[(size_t)h * 4096 + i];
    wo[i >> 6][i & 63] = Wo[(size_t)(h * 64 + (i >> 6)) * 512 + ct * 64 + (i & 63)];
  }
  __syncthreads();
  int cl = t & 63, dg = (t >> 6) * 16;
  float accv[16];
#pragma unroll
  for (int j = 0; j < 16; ++j) accv[j] = 0.f;
  for (int e = 0; e < 64; ++e) {
    float w = wo[e][cl];
#pragma unroll
    for (int j = 0; j < 16; ++j) accv[j] = fmaf(cs[dg + j][e], w, accv[j]);
  }
  u16x8 o0, o1;
#pragma unroll
  for (int j = 0; j < 8; ++j) { o0[j] = f2bf(accv[j]); o1[j] = f2bf(accv[j + 8]); }
  unsigned short* dst = WPT + (size_t)(ct * 64 + cl) * 512 + h * 64 + dg;
  *(u16x8*)dst = o0;
  *(u16x8*)(dst + 8) = o1;
}

// ---------------------------------------------------------------------------
extern "C" void kernel_launch(void* const* d_in, const int* in_sizes, int n_in,
                              void* d_out, int out_size, void* d_ws, size_t ws_size,
                              hipStream_t stream) {
  const float* x_in  = (const float*)d_in[0];
  const float* ln1_g = (const float*)d_in[1];
  const float* ln1_b = (const float*)d_in[2];
  const float* Wq    = (const float*)d_in[3];
  const float* Wk    = (const float*)d_in[4];
  const float* Wv    = (const float*)d_in[5];
  const float* Wo    = (const float*)d_in[6];
  const float* bo    = (const float*)d_in[7];
  const float* ln2_g = (const float*)d_in[8];
  const float* ln2_b = (const float*)d_in[9];
  const float* W1    = (const float*)d_in[10];
  const float* b1    = (const float*)d_in[11];
  const float* W2    = (const float*)d_in[12];
  const float* b2    = (const float*)d_in[13];
  const float* projW = (const float*)d_in[14];
  const float* projb = (const float*)d_in[15];
  float* out = (float*)d_out;
  float* ws  = (float*)d_ws;
  constexpr size_t M1 = 1u << 20;

  float* CTXP = ws;                       // 1M f
  float* PM   = ws + 1 * M1;              // 64K f
  float* PS   = PM + 65536;               // 64K f
  float* CTX  = PS + 65536;               // 32K f
  unsigned short* Xr  = (unsigned short*)(ws + 2 * M1);   // 4M u16 (bf16 residual)
  unsigned short* Qb  = (unsigned short*)(ws + 4 * M1);   // 4M u16
  unsigned short* Kb  = (unsigned short*)(ws + 6 * M1);   // 4M u16
  unsigned short* Vb  = (unsigned short*)(ws + 8 * M1);   // 4M u16
  unsigned short* Hb  = (unsigned short*)(ws + 10 * M1);  // 4M u16
  unsigned short* FFH = (unsigned short*)(ws + 12 * M1);  // 16M u16
  unsigned short* WT  = (unsigned short*)(ws + 20 * M1);  // 8M u16
  unsigned short* WPT = (unsigned short*)(ws + 24 * M1);  // 256K u16 (W' 512x512)

  prep_kernel<<<10240, 256, 0, stream>>>(Wq, Wk, Wv, Wo, W1, W2, projW, WT,
                                         x_in, Xr, Hb, ln1_g, ln1_b);

  dim3 gqkv(1536 / 128, N_SEQ / 128);
  dim3 g512n(512 / 64, N_SEQ / 128);
  dim3 gff1(FFDIM / 128, N_SEQ / 128);
  dim3 gproj(LLMD / 128, N_SEQ / 128);

  for (int l = 0; l < NLAYER; ++l) {
    const unsigned short* WQKV = WT + (size_t)l * 1048576;
    const unsigned short* W1T  = WT + 2097152 + (size_t)l * 1048576;
    const unsigned short* W2T  = WT + 4194304 + (size_t)l * 1048576;

    qkv_gemm<<<gqkv, 256, 0, stream>>>(Hb, WQKV, Qb, Kb, Vb, PM, PS);
    ctx_kernel<<<dim3(32, NH), 256, 0, stream>>>(Kb, Vb, PM, PS, CTXP);
    ctx_reduce_kernel<<<128, 256, 0, stream>>>(CTXP, CTX);
    ctxw2_kernel<<<dim3(8, NH), 256, 0, stream>>>(CTX, Wo + (size_t)l * D * D, WPT);
    // x += q @ W' + bo  (bf16 residual, in-place)
    mgemm2<29, 64><<<g512n, 256, 0, stream>>>(Qb, WPT, bo + l * D, Xr, nullptr,
                                              Xr, N_SEQ, 512, 512);
    ln_bf16<<<N_SEQ / 4, 256, 0, stream>>>(Xr, Hb, ln2_g + l * D, ln2_b + l * D);
    // FF1 + bias + GELU -> FFH (bf16)
    mgemm2<27, 128><<<gff1, 256, 0, stream>>>(Hb, W1T, b1 + l * FFDIM, nullptr,
                                              nullptr, FFH, N_SEQ, FFDIM, 512);
    // FF2 + bias + residual -> Xr (bf16, in-place)
    mgemm2<29, 64><<<g512n, 256, 0, stream>>>(FFH, W2T, b2 + l * D, Xr, nullptr,
                                              Xr, N_SEQ, 512, 2048);
    if (l != NLAYER - 1)
      ln_bf16<<<N_SEQ / 4, 256, 0, stream>>>(Xr, Hb, ln1_g + (l + 1) * D,
                                             ln1_b + (l + 1) * D);
  }
  mgemm2<1, 128><<<gproj, 256, 0, stream>>>(Xr, WT + 6291456, projb, nullptr,
                                            out, nullptr, N_SEQ, LLMD, 512);
}